// Round 2
// baseline (1174.906 us; speedup 1.0000x reference)
//
#include <hip/hip_runtime.h>
#include <hip/hip_bf16.h>

// ---------------------------------------------------------------------------
// 2-layer GraphSAGE (mean aggr) on gfx950.
// R2 change: CSR build via two-phase radix partition (bucket = dst>>6) to
// kill the 16x write amplification of the single random scatter
// (R1: scatter_kernel 130us, WRITE_SIZE 105MB for 6.4MB payload).
// Pipeline:
//   memset -> prep weights -> bucket hist -> bucket scan (1 block)
//   -> part_scatter (edges -> bucket-ordered ebuf, streaming appends)
//   -> hist2 (node degree, localized atomics) -> 3-kernel scan
//   -> csr_scatter (bucket-local: offs window 256B, csr window ~4KB)
//   -> gather x = bf16(emb[x_idx]) -> L1 agg -> L1 GEMM -> L2 agg -> L2 GEMM
//   -> gather drug/se rows.
// ebuf overlays xA1 (dead before gather_x). ws ~110 MB.
// ---------------------------------------------------------------------------

typedef __bf16 bf16x8 __attribute__((ext_vector_type(8)));
typedef __bf16 bf16x4 __attribute__((ext_vector_type(4)));
typedef float  f32x4  __attribute__((ext_vector_type(4)));

#define ROWB 1024  // bytes per A row: 512 bf16 (K = 512 = [mean | x])

__device__ __forceinline__ void async_copy16(void* lds_dst, const void* g_src) {
  __builtin_amdgcn_global_load_lds(
      (const __attribute__((address_space(1))) void*)g_src,
      (__attribute__((address_space(3))) void*)lds_dst, 16, 0, 0);
}

// ---- CSR build: phase A (bucket partition) --------------------------------

__global__ void bucket_hist(const int* __restrict__ dst, int* __restrict__ bcnt, int E) {
  int e = blockIdx.x * 256 + threadIdx.x;
  if (e < E) atomicAdd(&bcnt[dst[e] >> 6], 1);
}

// single block, 1024 threads, nb <= 2048: exclusive scan -> boff, bpos
__global__ void bucket_scan(const int* __restrict__ bcnt, int* __restrict__ boff,
                            int* __restrict__ bpos, int nb) {
  __shared__ int s[2048];
  int t = threadIdx.x;
  for (int i = t; i < 2048; i += 1024) s[i] = (i < nb) ? bcnt[i] : 0;
  __syncthreads();
  for (int d = 1; d < 2048; d <<= 1) {
    // Jacobi step: all reads before all writes => correct Hillis-Steele
    int v0 = (t >= d) ? s[t - d] : 0;
    int v1 = (t + 1024 >= d) ? s[t + 1024 - d] : 0;
    __syncthreads();
    s[t] += v0; s[t + 1024] += v1;
    __syncthreads();
  }
  for (int i = t; i < nb; i += 1024) {
    int ex = s[i] - bcnt[i];
    boff[i] = ex; bpos[i] = ex;
  }
}

__global__ void part_scatter(const int* __restrict__ src, const int* __restrict__ dst,
                             int* __restrict__ bpos, int2* __restrict__ ebuf, int E) {
  int e = blockIdx.x * 256 + threadIdx.x;
  if (e < E) {
    int d = dst[e];
    int p = atomicAdd(&bpos[d >> 6], 1);
    ebuf[p] = make_int2(src[e], d);
  }
}

// ---- CSR build: phase B (node-level, bucket-localized) --------------------

__global__ void hist2(const int2* __restrict__ ebuf, int* __restrict__ cnt, int E) {
  int e = blockIdx.x * 256 + threadIdx.x;
  if (e < E) atomicAdd(&cnt[ebuf[e].y], 1);
}

__global__ void scan_block_sums(const int* __restrict__ cnt, int* __restrict__ bsum, int n) {
  __shared__ int s[256];
  int i = blockIdx.x * 256 + threadIdx.x;
  s[threadIdx.x] = (i < n) ? cnt[i] : 0;
  __syncthreads();
  for (int d = 128; d > 0; d >>= 1) {
    if (threadIdx.x < d) s[threadIdx.x] += s[threadIdx.x + d];
    __syncthreads();
  }
  if (threadIdx.x == 0) bsum[blockIdx.x] = s[0];
}

__global__ void scan_tops(const int* __restrict__ bsum, int* __restrict__ bbase, int nb) {
  __shared__ int s[512];
  int t = threadIdx.x;
  int v = (t < nb) ? bsum[t] : 0;
  s[t] = v; __syncthreads();
  for (int d = 1; d < 512; d <<= 1) {
    int add = (t >= d) ? s[t - d] : 0;
    __syncthreads();
    s[t] += add;
    __syncthreads();
  }
  if (t < nb) bbase[t] = s[t] - v;  // exclusive
}

__global__ void scan_final(const int* __restrict__ cnt, const int* __restrict__ bbase,
                           int* __restrict__ offs, int n) {
  __shared__ int s[256];
  int t = threadIdx.x, i = blockIdx.x * 256 + t;
  int v = (i < n) ? cnt[i] : 0;
  s[t] = v; __syncthreads();
  for (int d = 1; d < 256; d <<= 1) {
    int add = (t >= d) ? s[t - d] : 0;
    __syncthreads();
    s[t] += add;
    __syncthreads();
  }
  if (i < n) offs[i] = bbase[blockIdx.x] + s[t] - v;  // exclusive start
}

__global__ void csr_scatter(const int2* __restrict__ ebuf, int* __restrict__ offs,
                            int* __restrict__ csr, int E) {
  int e = blockIdx.x * 256 + threadIdx.x;
  if (e < E) {
    int2 ed = ebuf[e];
    int p = atomicAdd(&offs[ed.y], 1);  // offs ends at segment END
    csr[p] = ed.x;
  }
}

// ---- feature prep ---------------------------------------------------------

// Wt[n][k] = bf16( k<256 ? Wl[k][n] : Wr[k-256][n] ), row-major [256][512]
__global__ void prep_w_kernel(const float* __restrict__ W1l, const float* __restrict__ W1r,
                              const float* __restrict__ W2l, const float* __restrict__ W2r,
                              __bf16* __restrict__ Wt1, __bf16* __restrict__ Wt2) {
  int idx = blockIdx.x * 256 + threadIdx.x;  // 0 .. 2*131072-1
  int which = idx >> 17;
  int j = idx & 131071;
  int n = j >> 9, k = j & 511;
  const float* Wl = which ? W2l : W1l;
  const float* Wr = which ? W2r : W1r;
  float v = (k < 256) ? Wl[k * 256 + n] : Wr[(k - 256) * 256 + n];
  (which ? Wt2 : Wt1)[j] = (__bf16)v;
}

// x-half gather: xbase points at (row stride ROWB) destination of the x slot
__global__ void gather_x_kernel(const float* __restrict__ emb, const int* __restrict__ x_idx,
                                char* __restrict__ xbase, int N) {
  int wave = threadIdx.x >> 6, lane = threadIdx.x & 63;
  int i = blockIdx.x * 4 + wave;
  if (i >= N) return;
  int s = x_idx[i];
  float4 v = *(const float4*)(emb + (size_t)s * 256 + lane * 4);
  bf16x4 o = { (__bf16)v.x, (__bf16)v.y, (__bf16)v.z, (__bf16)v.w };
  *(bf16x4*)(xbase + (size_t)i * ROWB + lane * 8) = o;
}

// ---- mean aggregation (gather-only, one wave per node) --------------------

__global__ void sage_agg(const char* __restrict__ srcbase,  // row r: srcbase + r*ROWB, 256 bf16
                         char* __restrict__ dstbase,        // node i: dstbase + i*ROWB, 256 bf16
                         const int* __restrict__ csr, const int* __restrict__ cnt,
                         const int* __restrict__ off_end, int N) {
  int wave = threadIdx.x >> 6, lane = threadIdx.x & 63;
  int i = blockIdx.x * 4 + wave;
  if (i >= N) return;
  int deg = cnt[i];
  int start = off_end[i] - deg;
  const int* lp = csr + start;
  float a0 = 0.f, a1 = 0.f, a2 = 0.f, a3 = 0.f;
  int j = 0;
  for (; j + 1 < deg; j += 2) {  // unroll-2: pipeline the dependent loads
    int s0 = lp[j], s1 = lp[j + 1];
    bf16x4 v0 = *(const bf16x4*)(srcbase + (size_t)s0 * ROWB + lane * 8);
    bf16x4 v1 = *(const bf16x4*)(srcbase + (size_t)s1 * ROWB + lane * 8);
    a0 += (float)v0[0] + (float)v1[0];
    a1 += (float)v0[1] + (float)v1[1];
    a2 += (float)v0[2] + (float)v1[2];
    a3 += (float)v0[3] + (float)v1[3];
  }
  if (j < deg) {
    int s0 = lp[j];
    bf16x4 v0 = *(const bf16x4*)(srcbase + (size_t)s0 * ROWB + lane * 8);
    a0 += (float)v0[0]; a1 += (float)v0[1]; a2 += (float)v0[2]; a3 += (float)v0[3];
  }
  float inv = 1.0f / (float)(deg > 0 ? deg : 1);
  bf16x4 o = { (__bf16)(a0 * inv), (__bf16)(a1 * inv), (__bf16)(a2 * inv), (__bf16)(a3 * inv) };
  *(bf16x4*)(dstbase + (size_t)i * ROWB + lane * 8) = o;
}

// ---- fused GEMM: out[M,256] = A[M,512] @ Wcat[512,256] + bias -------------
// BM=64, BN=256 (full), BK=32, 256 threads = 4 waves, wave tile 32x128.

template <int OUT_F32>
__global__ __launch_bounds__(256) void gemm_sage(const char* __restrict__ Abase,
                                                 const __bf16* __restrict__ Wt,
                                                 const float* __restrict__ bias,
                                                 char* __restrict__ outbase, int M) {
  __shared__ __align__(16) char lds[40960];  // 2 bufs x (A 4KB + B 16KB)
  const int tid = threadIdx.x;
  const int wave = tid >> 6, lane = tid & 63;
  const int r = lane & 15, q = lane >> 4;
  const int wm = wave >> 1, wn = wave & 1;
  const int row0 = blockIdx.x * 64;

  f32x4 acc[2][8];
#pragma unroll
  for (int t = 0; t < 2; ++t)
#pragma unroll
    for (int u = 0; u < 8; ++u) acc[t][u] = (f32x4)0.f;

  auto stage = [&](int kk, int buf) {
    char* lbase = lds + buf * 20480;
    int rowA = row0 + wave * 16 + r;
    rowA = rowA < M ? rowA : M - 1;  // clamp: garbage rows masked at store
    async_copy16(lbase + wave * 1024 + lane * 16,
                 Abase + (size_t)rowA * ROWB + (size_t)(kk * 32 + q * 8) * 2);
#pragma unroll
    for (int i = 0; i < 4; ++i) {
      int h = wave * 4 + i;
      async_copy16(lbase + 4096 + h * 1024 + lane * 16,
                   (const char*)Wt + ((size_t)(h * 16 + r) * 512 + kk * 32 + q * 8) * 2);
    }
  };

  stage(0, 0);
  for (int kk = 0; kk < 16; ++kk) {
    __syncthreads();  // compiler drains vmcnt before s_barrier -> staging done
    if (kk < 15) stage(kk + 1, (kk + 1) & 1);
    const char* lbase = lds + (kk & 1) * 20480;
    bf16x8 a0 = *(const bf16x8*)(lbase + (wm * 2 + 0) * 1024 + lane * 16);
    bf16x8 a1 = *(const bf16x8*)(lbase + (wm * 2 + 1) * 1024 + lane * 16);
#pragma unroll
    for (int u = 0; u < 8; ++u) {
      bf16x8 b = *(const bf16x8*)(lbase + 4096 + (wn * 8 + u) * 1024 + lane * 16);
      acc[0][u] = __builtin_amdgcn_mfma_f32_16x16x32_bf16(a0, b, acc[0][u], 0, 0, 0);
      acc[1][u] = __builtin_amdgcn_mfma_f32_16x16x32_bf16(a1, b, acc[1][u], 0, 0, 0);
    }
  }

  // epilogue. All global A reads drained at the kk=15 barrier, so in-place
  // fp32 overwrite of this block's own rows (sole owner, BN=256) is safe.
#pragma unroll
  for (int t = 0; t < 2; ++t) {
    int rbase = row0 + wm * 32 + t * 16 + q * 4;
#pragma unroll
    for (int u = 0; u < 8; ++u) {
      int col = wn * 128 + u * 16 + r;
      float bv = bias[col];
#pragma unroll
      for (int j = 0; j < 4; ++j) {
        int row = rbase + j;
        if (row < M) {
          float v = acc[t][u][j] + bv;
          if (OUT_F32)
            *(float*)(outbase + (size_t)row * ROWB + col * 4) = v;
          else
            *(__bf16*)(outbase + (size_t)row * ROWB + 512 + col * 2) = (__bf16)v;
        }
      }
    }
  }
}

// ---- final index gathers --------------------------------------------------

__global__ void gather_out_kernel(const float* __restrict__ x2, const int* __restrict__ drug,
                                  const int* __restrict__ se, float* __restrict__ out,
                                  int nd, int ns) {
  int wave = threadIdx.x >> 6, lane = threadIdx.x & 63;
  int ro = blockIdx.x * 4 + wave;
  if (ro >= nd + ns) return;
  int node = (ro < nd) ? drug[ro] : se[ro - nd];
  float4 v = *(const float4*)(x2 + (size_t)node * 256 + lane * 4);
  *(float4*)(out + (size_t)ro * 256 + lane * 4) = v;
}

// ---------------------------------------------------------------------------

extern "C" void kernel_launch(void* const* d_in, const int* in_sizes, int n_in,
                              void* d_out, int out_size, void* d_ws, size_t ws_size,
                              hipStream_t stream) {
  const float* emb  = (const float*)d_in[0];
  const float* W1l  = (const float*)d_in[1];
  const float* b1l  = (const float*)d_in[2];
  const float* W1r  = (const float*)d_in[3];
  const float* W2l  = (const float*)d_in[4];
  const float* b2l  = (const float*)d_in[5];
  const float* W2r  = (const float*)d_in[6];
  const int* x_idx  = (const int*)d_in[7];
  const int* edge   = (const int*)d_in[8];
  const int* drug   = (const int*)d_in[9];
  const int* se     = (const int*)d_in[10];

  const int N = in_sizes[7];       // 100000
  const int E = in_sizes[8] / 2;   // 1600000
  const int nd = in_sizes[9], ns = in_sizes[10];
  const int* esrc = edge;
  const int* edst = edge + E;
  const int NBUK = (N + 63) >> 6;  // 1563 (<=2048 required by bucket_scan)

  // workspace carve (~110 MB)
  char* ws = (char*)d_ws;
  size_t off = 0;
  char* xA1 = ws;                       off += (size_t)((N + 127) & ~127) * ROWB;
  __bf16* Wt1 = (__bf16*)(ws + off);    off += 512 * 256 * 2;
  __bf16* Wt2 = (__bf16*)(ws + off);    off += 512 * 256 * 2;
  int* cnt  = (int*)(ws + off);         off += ((size_t)N * 4 + 255) & ~(size_t)255;
  int* offs = (int*)(ws + off);         off += ((size_t)N * 4 + 255) & ~(size_t)255;
  int* csr  = (int*)(ws + off);         off += ((size_t)E * 4 + 255) & ~(size_t)255;
  int* bsum = (int*)(ws + off);         off += 4096;
  int* bbase = (int*)(ws + off);        off += 4096;
  int* bcnt = (int*)(ws + off);         off += 8192;
  int* boff = (int*)(ws + off);         off += 8192;
  int* bpos = (int*)(ws + off);         off += 8192;
  // ebuf overlays xA1: dead before gather_x_kernel writes xA1 (stream order)
  int2* ebuf = (int2*)xA1;

  // d_out carve: [drug nd*256 | se ns*256 | x2 N*256] fp32
  float* outp = (float*)d_out;
  float* x2 = outp + (size_t)(nd + ns) * 256;
  char* scratch2 = (char*)x2;  // rows of 1KB: [mean2 bf16 | x1 bf16] -> x2 fp32

  const int NB = (N + 255) / 256;        // 391 (<=512 required by scan_tops)
  const int EB = (E + 255) / 256;
  const int QB = (N + 3) / 4;
  const int GB = (N + 63) / 64;

  hipMemsetAsync(cnt, 0, (size_t)N * 4, stream);
  hipMemsetAsync(bcnt, 0, (size_t)NBUK * 4, stream);
  prep_w_kernel<<<(2 * 131072) / 256, 256, 0, stream>>>(W1l, W1r, W2l, W2r, Wt1, Wt2);

  // CSR build, two-phase
  bucket_hist<<<EB, 256, 0, stream>>>(edst, bcnt, E);
  bucket_scan<<<1, 1024, 0, stream>>>(bcnt, boff, bpos, NBUK);
  part_scatter<<<EB, 256, 0, stream>>>(esrc, edst, bpos, ebuf, E);
  hist2<<<EB, 256, 0, stream>>>(ebuf, cnt, E);
  scan_block_sums<<<NB, 256, 0, stream>>>(cnt, bsum, N);
  scan_tops<<<1, 512, 0, stream>>>(bsum, bbase, NB);
  scan_final<<<NB, 256, 0, stream>>>(cnt, bbase, offs, N);
  csr_scatter<<<EB, 256, 0, stream>>>(ebuf, offs, csr, E);

  gather_x_kernel<<<QB, 256, 0, stream>>>(emb, x_idx, xA1 + 512, N);
  // layer 1
  sage_agg<<<QB, 256, 0, stream>>>(xA1 + 512, xA1, csr, cnt, offs, N);
  gemm_sage<0><<<GB, 256, 0, stream>>>(xA1, Wt1, b1l, scratch2, N);
  // layer 2
  sage_agg<<<QB, 256, 0, stream>>>(scratch2 + 512, scratch2, csr, cnt, offs, N);
  gemm_sage<1><<<GB, 256, 0, stream>>>(scratch2, Wt2, b2l, scratch2, N);

  gather_out_kernel<<<(nd + ns + 3) / 4, 256, 0, stream>>>(x2, drug, se, outp, nd, ns);
}

// Round 3
// 715.522 us; speedup vs baseline: 1.6420x; 1.6420x over previous
//
#include <hip/hip_runtime.h>
#include <hip/hip_bf16.h>

// ---------------------------------------------------------------------------
// 2-layer GraphSAGE (mean aggr) on gfx950.
// R3: CSR build is fully deterministic (no contended global atomics).
//   bin_count   : per-block LDS hist over 1563 buckets -> hmat[128][1563]
//   col_scan    : exclusive scan per bucket across blocks -> windows + btot
//   bucket_scan : exclusive scan of btot -> boff (1 block)
//   part_write  : edges -> bucket-ordered ebuf (packed src|dloc<<18),
//                 LDS cursors, disjoint windows, zero global atomics
//   node_hist   : block-per-bucket degree hist -> cnt (direct store)
//   3-kernel scan -> offs (exclusive start)
//   csr_write   : block-per-bucket, LDS cursors, csr writes in 4KB window
// Then: gather_x -> L1 agg -> L1 GEMM -> L2 agg -> L2 GEMM -> out gathers.
// ebuf/hmat/btot/boff overlay xA1 (dead before gather_x). ws ~110 MB.
// ---------------------------------------------------------------------------

typedef __bf16 bf16x8 __attribute__((ext_vector_type(8)));
typedef __bf16 bf16x4 __attribute__((ext_vector_type(4)));
typedef float  f32x4  __attribute__((ext_vector_type(4)));

#define ROWB 1024   // bytes per A row: 512 bf16 (K = 512 = [mean | x])
#define NPART 128   // partition blocks
#define MAXBUK 2048 // bucket capacity bound (N<=131072)

__device__ __forceinline__ void async_copy16(void* lds_dst, const void* g_src) {
  __builtin_amdgcn_global_load_lds(
      (const __attribute__((address_space(1))) void*)g_src,
      (__attribute__((address_space(3))) void*)lds_dst, 16, 0, 0);
}

// ---- CSR build ------------------------------------------------------------

// block p: LDS histogram of dst>>6 over its chunk -> hmat[p][:]
__global__ void bin_count(const int* __restrict__ dst, int* __restrict__ hmat,
                          int E, int chunk, int nbuk) {
  __shared__ int lh[MAXBUK];
  int p = blockIdx.x, tid = threadIdx.x;
  for (int i = tid; i < nbuk; i += 256) lh[i] = 0;
  __syncthreads();
  int base = p * chunk, end = min(base + chunk, E);
  for (int e = base + tid; e < end; e += 256) atomicAdd(&lh[dst[e] >> 6], 1);
  __syncthreads();
  for (int i = tid; i < nbuk; i += 256) hmat[p * nbuk + i] = lh[i];
}

// block b: exclusive scan of hmat[0..NPART-1][b]; btot[b] = total
__global__ void col_scan(int* __restrict__ hmat, int* __restrict__ btot, int nbuk) {
  __shared__ int s[NPART];
  int b = blockIdx.x, t = threadIdx.x;  // 128 threads
  int v = hmat[t * nbuk + b];
  s[t] = v; __syncthreads();
  for (int d = 1; d < NPART; d <<= 1) {
    int add = (t >= d) ? s[t - d] : 0;
    __syncthreads();
    s[t] += add;
    __syncthreads();
  }
  hmat[t * nbuk + b] = s[t] - v;  // exclusive within bucket
  if (t == NPART - 1) btot[b] = s[t];
}

// single block, 1024 threads, nb <= 2048: exclusive scan btot -> boff
__global__ void bucket_scan(const int* __restrict__ btot, int* __restrict__ boff, int nb) {
  __shared__ int s[2048];
  int t = threadIdx.x;
  for (int i = t; i < 2048; i += 1024) s[i] = (i < nb) ? btot[i] : 0;
  __syncthreads();
  for (int d = 1; d < 2048; d <<= 1) {
    int v0 = (t >= d) ? s[t - d] : 0;
    int v1 = (t + 1024 >= d) ? s[t + 1024 - d] : 0;
    __syncthreads();
    s[t] += v0; s[t + 1024] += v1;
    __syncthreads();
  }
  for (int i = t; i < nb; i += 1024) boff[i] = s[i] - btot[i];
}

// block p: write its chunk's edges into disjoint per-bucket windows.
// entry = src | ((dst&63) << 18)   (src < 2^18)
__global__ void part_write(const int* __restrict__ src, const int* __restrict__ dst,
                           const int* __restrict__ hmat, const int* __restrict__ boff,
                           int* __restrict__ ebuf, int E, int chunk, int nbuk) {
  __shared__ int cur[MAXBUK];
  int p = blockIdx.x, tid = threadIdx.x;
  for (int i = tid; i < nbuk; i += 256) cur[i] = hmat[p * nbuk + i] + boff[i];
  __syncthreads();
  int base = p * chunk, end = min(base + chunk, E);
  for (int e = base + tid; e < end; e += 256) {
    int d = dst[e];
    int pos = atomicAdd(&cur[d >> 6], 1);  // LDS atomic, ~8 hits/counter
    ebuf[pos] = src[e] | ((d & 63) << 18);
  }
}

// block b: degree histogram of its 64 nodes (direct store, no memset needed)
__global__ void node_hist(const int* __restrict__ ebuf, const int* __restrict__ boff,
                          const int* __restrict__ btot, int* __restrict__ cnt, int N) {
  __shared__ int lh[64];
  int b = blockIdx.x, tid = threadIdx.x;
  if (tid < 64) lh[tid] = 0;
  __syncthreads();
  int s0 = boff[b], s1 = s0 + btot[b];
  for (int i = s0 + tid; i < s1; i += 256) atomicAdd(&lh[ebuf[i] >> 18], 1);
  __syncthreads();
  int node = b * 64 + tid;
  if (tid < 64 && node < N) cnt[node] = lh[tid];
}

__global__ void scan_block_sums(const int* __restrict__ cnt, int* __restrict__ bsum, int n) {
  __shared__ int s[256];
  int i = blockIdx.x * 256 + threadIdx.x;
  s[threadIdx.x] = (i < n) ? cnt[i] : 0;
  __syncthreads();
  for (int d = 128; d > 0; d >>= 1) {
    if (threadIdx.x < d) s[threadIdx.x] += s[threadIdx.x + d];
    __syncthreads();
  }
  if (threadIdx.x == 0) bsum[blockIdx.x] = s[0];
}

__global__ void scan_tops(const int* __restrict__ bsum, int* __restrict__ bbase, int nb) {
  __shared__ int s[512];
  int t = threadIdx.x;
  int v = (t < nb) ? bsum[t] : 0;
  s[t] = v; __syncthreads();
  for (int d = 1; d < 512; d <<= 1) {
    int add = (t >= d) ? s[t - d] : 0;
    __syncthreads();
    s[t] += add;
    __syncthreads();
  }
  if (t < nb) bbase[t] = s[t] - v;  // exclusive
}

__global__ void scan_final(const int* __restrict__ cnt, const int* __restrict__ bbase,
                           int* __restrict__ offs, int n) {
  __shared__ int s[256];
  int t = threadIdx.x, i = blockIdx.x * 256 + t;
  int v = (i < n) ? cnt[i] : 0;
  s[t] = v; __syncthreads();
  for (int d = 1; d < 256; d <<= 1) {
    int add = (t >= d) ? s[t - d] : 0;
    __syncthreads();
    s[t] += add;
    __syncthreads();
  }
  if (i < n) offs[i] = bbase[blockIdx.x] + s[t] - v;  // exclusive START
}

// block b: place its bucket's edges into csr via LDS cursors (4KB window)
__global__ void csr_write(const int* __restrict__ ebuf, const int* __restrict__ boff,
                          const int* __restrict__ btot, const int* __restrict__ offs,
                          int* __restrict__ csr, int N) {
  __shared__ int cur[64];
  int b = blockIdx.x, tid = threadIdx.x;
  int node = b * 64 + tid;
  if (tid < 64) cur[tid] = (node < N) ? offs[node] : 0;
  __syncthreads();
  int s0 = boff[b], s1 = s0 + btot[b];
  for (int i = s0 + tid; i < s1; i += 256) {
    int e = ebuf[i];
    int p = atomicAdd(&cur[e >> 18], 1);
    csr[p] = e & 0x3FFFF;
  }
}

// ---- feature prep ---------------------------------------------------------

// Wt[n][k] = bf16( k<256 ? Wl[k][n] : Wr[k-256][n] ), row-major [256][512]
__global__ void prep_w_kernel(const float* __restrict__ W1l, const float* __restrict__ W1r,
                              const float* __restrict__ W2l, const float* __restrict__ W2r,
                              __bf16* __restrict__ Wt1, __bf16* __restrict__ Wt2) {
  int idx = blockIdx.x * 256 + threadIdx.x;  // 0 .. 2*131072-1
  int which = idx >> 17;
  int j = idx & 131071;
  int n = j >> 9, k = j & 511;
  const float* Wl = which ? W2l : W1l;
  const float* Wr = which ? W2r : W1r;
  float v = (k < 256) ? Wl[k * 256 + n] : Wr[(k - 256) * 256 + n];
  (which ? Wt2 : Wt1)[j] = (__bf16)v;
}

// x-half gather: xbase points at (row stride ROWB) destination of the x slot
__global__ void gather_x_kernel(const float* __restrict__ emb, const int* __restrict__ x_idx,
                                char* __restrict__ xbase, int N) {
  int wave = threadIdx.x >> 6, lane = threadIdx.x & 63;
  int i = blockIdx.x * 4 + wave;
  if (i >= N) return;
  int s = x_idx[i];
  float4 v = *(const float4*)(emb + (size_t)s * 256 + lane * 4);
  bf16x4 o = { (__bf16)v.x, (__bf16)v.y, (__bf16)v.z, (__bf16)v.w };
  *(bf16x4*)(xbase + (size_t)i * ROWB + lane * 8) = o;
}

// ---- mean aggregation (gather-only, one wave per node) --------------------

__global__ void sage_agg(const char* __restrict__ srcbase,  // row r: srcbase + r*ROWB, 256 bf16
                         char* __restrict__ dstbase,        // node i: dstbase + i*ROWB, 256 bf16
                         const int* __restrict__ csr, const int* __restrict__ cnt,
                         const int* __restrict__ offs, int N) {
  int wave = threadIdx.x >> 6, lane = threadIdx.x & 63;
  int i = blockIdx.x * 4 + wave;
  if (i >= N) return;
  int deg = cnt[i];
  int start = offs[i];
  const int* lp = csr + start;
  float a0 = 0.f, a1 = 0.f, a2 = 0.f, a3 = 0.f;
  int j = 0;
  for (; j + 1 < deg; j += 2) {  // unroll-2: pipeline the independent loads
    int s0 = lp[j], s1 = lp[j + 1];
    bf16x4 v0 = *(const bf16x4*)(srcbase + (size_t)s0 * ROWB + lane * 8);
    bf16x4 v1 = *(const bf16x4*)(srcbase + (size_t)s1 * ROWB + lane * 8);
    a0 += (float)v0[0] + (float)v1[0];
    a1 += (float)v0[1] + (float)v1[1];
    a2 += (float)v0[2] + (float)v1[2];
    a3 += (float)v0[3] + (float)v1[3];
  }
  if (j < deg) {
    int s0 = lp[j];
    bf16x4 v0 = *(const bf16x4*)(srcbase + (size_t)s0 * ROWB + lane * 8);
    a0 += (float)v0[0]; a1 += (float)v0[1]; a2 += (float)v0[2]; a3 += (float)v0[3];
  }
  float inv = 1.0f / (float)(deg > 0 ? deg : 1);
  bf16x4 o = { (__bf16)(a0 * inv), (__bf16)(a1 * inv), (__bf16)(a2 * inv), (__bf16)(a3 * inv) };
  *(bf16x4*)(dstbase + (size_t)i * ROWB + lane * 8) = o;
}

// ---- fused GEMM: out[M,256] = A[M,512] @ Wcat[512,256] + bias -------------
// BM=64, BN=256 (full), BK=32, 256 threads = 4 waves, wave tile 32x128.

template <int OUT_F32>
__global__ __launch_bounds__(256) void gemm_sage(const char* __restrict__ Abase,
                                                 const __bf16* __restrict__ Wt,
                                                 const float* __restrict__ bias,
                                                 char* __restrict__ outbase, int M) {
  __shared__ __align__(16) char lds[40960];  // 2 bufs x (A 4KB + B 16KB)
  const int tid = threadIdx.x;
  const int wave = tid >> 6, lane = tid & 63;
  const int r = lane & 15, q = lane >> 4;
  const int wm = wave >> 1, wn = wave & 1;
  const int row0 = blockIdx.x * 64;

  f32x4 acc[2][8];
#pragma unroll
  for (int t = 0; t < 2; ++t)
#pragma unroll
    for (int u = 0; u < 8; ++u) acc[t][u] = (f32x4)0.f;

  auto stage = [&](int kk, int buf) {
    char* lbase = lds + buf * 20480;
    int rowA = row0 + wave * 16 + r;
    rowA = rowA < M ? rowA : M - 1;  // clamp: garbage rows masked at store
    async_copy16(lbase + wave * 1024 + lane * 16,
                 Abase + (size_t)rowA * ROWB + (size_t)(kk * 32 + q * 8) * 2);
#pragma unroll
    for (int i = 0; i < 4; ++i) {
      int h = wave * 4 + i;
      async_copy16(lbase + 4096 + h * 1024 + lane * 16,
                   (const char*)Wt + ((size_t)(h * 16 + r) * 512 + kk * 32 + q * 8) * 2);
    }
  };

  stage(0, 0);
  for (int kk = 0; kk < 16; ++kk) {
    __syncthreads();  // compiler drains vmcnt before s_barrier -> staging done
    if (kk < 15) stage(kk + 1, (kk + 1) & 1);
    const char* lbase = lds + (kk & 1) * 20480;
    bf16x8 a0 = *(const bf16x8*)(lbase + (wm * 2 + 0) * 1024 + lane * 16);
    bf16x8 a1 = *(const bf16x8*)(lbase + (wm * 2 + 1) * 1024 + lane * 16);
#pragma unroll
    for (int u = 0; u < 8; ++u) {
      bf16x8 b = *(const bf16x8*)(lbase + 4096 + (wn * 8 + u) * 1024 + lane * 16);
      acc[0][u] = __builtin_amdgcn_mfma_f32_16x16x32_bf16(a0, b, acc[0][u], 0, 0, 0);
      acc[1][u] = __builtin_amdgcn_mfma_f32_16x16x32_bf16(a1, b, acc[1][u], 0, 0, 0);
    }
  }

  // epilogue. All global A reads drained at the kk=15 barrier, so in-place
  // fp32 overwrite of this block's own rows (sole owner, BN=256) is safe.
#pragma unroll
  for (int t = 0; t < 2; ++t) {
    int rbase = row0 + wm * 32 + t * 16 + q * 4;
#pragma unroll
    for (int u = 0; u < 8; ++u) {
      int col = wn * 128 + u * 16 + r;
      float bv = bias[col];
#pragma unroll
      for (int j = 0; j < 4; ++j) {
        int row = rbase + j;
        if (row < M) {
          float v = acc[t][u][j] + bv;
          if (OUT_F32)
            *(float*)(outbase + (size_t)row * ROWB + col * 4) = v;
          else
            *(__bf16*)(outbase + (size_t)row * ROWB + 512 + col * 2) = (__bf16)v;
        }
      }
    }
  }
}

// ---- final index gathers --------------------------------------------------

__global__ void gather_out_kernel(const float* __restrict__ x2, const int* __restrict__ drug,
                                  const int* __restrict__ se, float* __restrict__ out,
                                  int nd, int ns) {
  int wave = threadIdx.x >> 6, lane = threadIdx.x & 63;
  int ro = blockIdx.x * 4 + wave;
  if (ro >= nd + ns) return;
  int node = (ro < nd) ? drug[ro] : se[ro - nd];
  float4 v = *(const float4*)(x2 + (size_t)node * 256 + lane * 4);
  *(float4*)(out + (size_t)ro * 256 + lane * 4) = v;
}

// ---------------------------------------------------------------------------

extern "C" void kernel_launch(void* const* d_in, const int* in_sizes, int n_in,
                              void* d_out, int out_size, void* d_ws, size_t ws_size,
                              hipStream_t stream) {
  const float* emb  = (const float*)d_in[0];
  const float* W1l  = (const float*)d_in[1];
  const float* b1l  = (const float*)d_in[2];
  const float* W1r  = (const float*)d_in[3];
  const float* W2l  = (const float*)d_in[4];
  const float* b2l  = (const float*)d_in[5];
  const float* W2r  = (const float*)d_in[6];
  const int* x_idx  = (const int*)d_in[7];
  const int* edge   = (const int*)d_in[8];
  const int* drug   = (const int*)d_in[9];
  const int* se     = (const int*)d_in[10];

  const int N = in_sizes[7];       // 100000
  const int E = in_sizes[8] / 2;   // 1600000
  const int nd = in_sizes[9], ns = in_sizes[10];
  const int* esrc = edge;
  const int* edst = edge + E;
  const int NBUK = (N + 63) >> 6;  // 1563 (<= MAXBUK)
  const int chunk = (E + NPART - 1) / NPART;

  // persistent workspace carve (~110 MB)
  char* ws = (char*)d_ws;
  size_t off = 0;
  char* xA1 = ws;                       off += (size_t)((N + 127) & ~127) * ROWB;
  __bf16* Wt1 = (__bf16*)(ws + off);    off += 512 * 256 * 2;
  __bf16* Wt2 = (__bf16*)(ws + off);    off += 512 * 256 * 2;
  int* cnt  = (int*)(ws + off);         off += ((size_t)N * 4 + 255) & ~(size_t)255;
  int* offs = (int*)(ws + off);         off += ((size_t)N * 4 + 255) & ~(size_t)255;
  int* csr  = (int*)(ws + off);         off += ((size_t)E * 4 + 255) & ~(size_t)255;
  int* bsum = (int*)(ws + off);         off += 4096;
  int* bbase = (int*)(ws + off);        off += 4096;
  // transient arrays overlay xA1 (all dead before gather_x writes xA1):
  int* ebuf = (int*)xA1;                         // E ints (6.4 MB)
  int* hmat = (int*)(xA1 + (8u << 20));          // NPART*NBUK ints (~0.8 MB)
  int* btot = (int*)(xA1 + (16u << 20));         // NBUK ints
  int* boff = (int*)(xA1 + (16u << 20) + 16384); // NBUK ints

  // d_out carve: [drug nd*256 | se ns*256 | x2 N*256] fp32
  float* outp = (float*)d_out;
  float* x2 = outp + (size_t)(nd + ns) * 256;
  char* scratch2 = (char*)x2;  // rows of 1KB: [mean2 bf16 | x1 bf16] -> x2 fp32

  const int NB = (N + 255) / 256;        // 391 (<=512 required by scan_tops)
  const int QB = (N + 3) / 4;
  const int GB = (N + 63) / 64;

  prep_w_kernel<<<(2 * 131072) / 256, 256, 0, stream>>>(W1l, W1r, W2l, W2r, Wt1, Wt2);

  // CSR build, deterministic (no global atomics)
  bin_count<<<NPART, 256, 0, stream>>>(edst, hmat, E, chunk, NBUK);
  col_scan<<<NBUK, NPART, 0, stream>>>(hmat, btot, NBUK);
  bucket_scan<<<1, 1024, 0, stream>>>(btot, boff, NBUK);
  part_write<<<NPART, 256, 0, stream>>>(esrc, edst, hmat, boff, ebuf, E, chunk, NBUK);
  node_hist<<<NBUK, 256, 0, stream>>>(ebuf, boff, btot, cnt, N);
  scan_block_sums<<<NB, 256, 0, stream>>>(cnt, bsum, N);
  scan_tops<<<1, 512, 0, stream>>>(bsum, bbase, NB);
  scan_final<<<NB, 256, 0, stream>>>(cnt, bbase, offs, N);
  csr_write<<<NBUK, 256, 0, stream>>>(ebuf, boff, btot, offs, csr, N);

  gather_x_kernel<<<QB, 256, 0, stream>>>(emb, x_idx, xA1 + 512, N);
  // layer 1
  sage_agg<<<QB, 256, 0, stream>>>(xA1 + 512, xA1, csr, cnt, offs, N);
  gemm_sage<0><<<GB, 256, 0, stream>>>(xA1, Wt1, b1l, scratch2, N);
  // layer 2
  sage_agg<<<QB, 256, 0, stream>>>(scratch2 + 512, scratch2, csr, cnt, offs, N);
  gemm_sage<1><<<GB, 256, 0, stream>>>(scratch2, Wt2, b2l, scratch2, N);

  gather_out_kernel<<<(nd + ns + 3) / 4, 256, 0, stream>>>(x2, drug, se, outp, nd, ns);
}

// Round 4
// 675.760 us; speedup vs baseline: 1.7386x; 1.0588x over previous
//
#include <hip/hip_runtime.h>
#include <hip/hip_bf16.h>

// ---------------------------------------------------------------------------
// 2-layer GraphSAGE (mean aggr) on gfx950.
// R4: sage_agg rework — two 32-lane halves each gather a different src row
// at 16B/lane (dwordx4): 1 instr = 2 rows (1KB), pair-unroll = 4 rows
// (2KB) in flight per wave. Cross-half reduce via shfl_down(32).
// Also NPART 128->256 (CSR partition kernels were on half the CUs).
// CSR build deterministic (R3): bin_count -> col_scan -> bucket_scan ->
// part_write -> node_hist -> scan -> csr_write. No contended global atomics.
// ---------------------------------------------------------------------------

typedef __bf16 bf16x8 __attribute__((ext_vector_type(8)));
typedef __bf16 bf16x4 __attribute__((ext_vector_type(4)));
typedef float  f32x4  __attribute__((ext_vector_type(4)));
typedef float  f32x8  __attribute__((ext_vector_type(8)));

#define ROWB 1024   // bytes per A row: 512 bf16 (K = 512 = [mean | x])
#define NPART 256   // partition blocks
#define MAXBUK 2048 // bucket capacity bound (N<=131072)

__device__ __forceinline__ void async_copy16(void* lds_dst, const void* g_src) {
  __builtin_amdgcn_global_load_lds(
      (const __attribute__((address_space(1))) void*)g_src,
      (__attribute__((address_space(3))) void*)lds_dst, 16, 0, 0);
}

// ---- CSR build ------------------------------------------------------------

// block p: LDS histogram of dst>>6 over its chunk -> hmat[p][:]
__global__ void bin_count(const int* __restrict__ dst, int* __restrict__ hmat,
                          int E, int chunk, int nbuk) {
  __shared__ int lh[MAXBUK];
  int p = blockIdx.x, tid = threadIdx.x;
  for (int i = tid; i < nbuk; i += 256) lh[i] = 0;
  __syncthreads();
  int base = p * chunk, end = min(base + chunk, E);
  for (int e = base + tid; e < end; e += 256) atomicAdd(&lh[dst[e] >> 6], 1);
  __syncthreads();
  for (int i = tid; i < nbuk; i += 256) hmat[p * nbuk + i] = lh[i];
}

// block b: exclusive scan of hmat[0..NPART-1][b]; btot[b] = total
__global__ void col_scan(int* __restrict__ hmat, int* __restrict__ btot, int nbuk) {
  __shared__ int s[NPART];
  int b = blockIdx.x, t = threadIdx.x;  // NPART threads
  int v = hmat[t * nbuk + b];
  s[t] = v; __syncthreads();
  for (int d = 1; d < NPART; d <<= 1) {
    int add = (t >= d) ? s[t - d] : 0;
    __syncthreads();
    s[t] += add;
    __syncthreads();
  }
  hmat[t * nbuk + b] = s[t] - v;  // exclusive within bucket
  if (t == NPART - 1) btot[b] = s[t];
}

// single block, 1024 threads, nb <= 2048: exclusive scan btot -> boff
__global__ void bucket_scan(const int* __restrict__ btot, int* __restrict__ boff, int nb) {
  __shared__ int s[2048];
  int t = threadIdx.x;
  for (int i = t; i < 2048; i += 1024) s[i] = (i < nb) ? btot[i] : 0;
  __syncthreads();
  for (int d = 1; d < 2048; d <<= 1) {
    int v0 = (t >= d) ? s[t - d] : 0;
    int v1 = (t + 1024 >= d) ? s[t + 1024 - d] : 0;
    __syncthreads();
    s[t] += v0; s[t + 1024] += v1;
    __syncthreads();
  }
  for (int i = t; i < nb; i += 1024) boff[i] = s[i] - btot[i];
}

// block p: write its chunk's edges into disjoint per-bucket windows.
// entry = src | ((dst&63) << 18)   (src < 2^18)
__global__ void part_write(const int* __restrict__ src, const int* __restrict__ dst,
                           const int* __restrict__ hmat, const int* __restrict__ boff,
                           int* __restrict__ ebuf, int E, int chunk, int nbuk) {
  __shared__ int cur[MAXBUK];
  int p = blockIdx.x, tid = threadIdx.x;
  for (int i = tid; i < nbuk; i += 256) cur[i] = hmat[p * nbuk + i] + boff[i];
  __syncthreads();
  int base = p * chunk, end = min(base + chunk, E);
  for (int e = base + tid; e < end; e += 256) {
    int d = dst[e];
    int pos = atomicAdd(&cur[d >> 6], 1);  // LDS atomic, low contention
    ebuf[pos] = src[e] | ((d & 63) << 18);
  }
}

// block b: degree histogram of its 64 nodes (direct store, no memset needed)
__global__ void node_hist(const int* __restrict__ ebuf, const int* __restrict__ boff,
                          const int* __restrict__ btot, int* __restrict__ cnt, int N) {
  __shared__ int lh[64];
  int b = blockIdx.x, tid = threadIdx.x;
  if (tid < 64) lh[tid] = 0;
  __syncthreads();
  int s0 = boff[b], s1 = s0 + btot[b];
  for (int i = s0 + tid; i < s1; i += 256) atomicAdd(&lh[ebuf[i] >> 18], 1);
  __syncthreads();
  int node = b * 64 + tid;
  if (tid < 64 && node < N) cnt[node] = lh[tid];
}

__global__ void scan_block_sums(const int* __restrict__ cnt, int* __restrict__ bsum, int n) {
  __shared__ int s[256];
  int i = blockIdx.x * 256 + threadIdx.x;
  s[threadIdx.x] = (i < n) ? cnt[i] : 0;
  __syncthreads();
  for (int d = 128; d > 0; d >>= 1) {
    if (threadIdx.x < d) s[threadIdx.x] += s[threadIdx.x + d];
    __syncthreads();
  }
  if (threadIdx.x == 0) bsum[blockIdx.x] = s[0];
}

__global__ void scan_tops(const int* __restrict__ bsum, int* __restrict__ bbase, int nb) {
  __shared__ int s[512];
  int t = threadIdx.x;
  int v = (t < nb) ? bsum[t] : 0;
  s[t] = v; __syncthreads();
  for (int d = 1; d < 512; d <<= 1) {
    int add = (t >= d) ? s[t - d] : 0;
    __syncthreads();
    s[t] += add;
    __syncthreads();
  }
  if (t < nb) bbase[t] = s[t] - v;  // exclusive
}

__global__ void scan_final(const int* __restrict__ cnt, const int* __restrict__ bbase,
                           int* __restrict__ offs, int n) {
  __shared__ int s[256];
  int t = threadIdx.x, i = blockIdx.x * 256 + t;
  int v = (i < n) ? cnt[i] : 0;
  s[t] = v; __syncthreads();
  for (int d = 1; d < 256; d <<= 1) {
    int add = (t >= d) ? s[t - d] : 0;
    __syncthreads();
    s[t] += add;
    __syncthreads();
  }
  if (i < n) offs[i] = bbase[blockIdx.x] + s[t] - v;  // exclusive START
}

// block b: place its bucket's edges into csr via LDS cursors (4KB window)
__global__ void csr_write(const int* __restrict__ ebuf, const int* __restrict__ boff,
                          const int* __restrict__ btot, const int* __restrict__ offs,
                          int* __restrict__ csr, int N) {
  __shared__ int cur[64];
  int b = blockIdx.x, tid = threadIdx.x;
  int node = b * 64 + tid;
  if (tid < 64) cur[tid] = (node < N) ? offs[node] : 0;
  __syncthreads();
  int s0 = boff[b], s1 = s0 + btot[b];
  for (int i = s0 + tid; i < s1; i += 256) {
    int e = ebuf[i];
    int p = atomicAdd(&cur[e >> 18], 1);
    csr[p] = e & 0x3FFFF;
  }
}

// ---- feature prep ---------------------------------------------------------

// Wt[n][k] = bf16( k<256 ? Wl[k][n] : Wr[k-256][n] ), row-major [256][512]
__global__ void prep_w_kernel(const float* __restrict__ W1l, const float* __restrict__ W1r,
                              const float* __restrict__ W2l, const float* __restrict__ W2r,
                              __bf16* __restrict__ Wt1, __bf16* __restrict__ Wt2) {
  int idx = blockIdx.x * 256 + threadIdx.x;  // 0 .. 2*131072-1
  int which = idx >> 17;
  int j = idx & 131071;
  int n = j >> 9, k = j & 511;
  const float* Wl = which ? W2l : W1l;
  const float* Wr = which ? W2r : W1r;
  float v = (k < 256) ? Wl[k * 256 + n] : Wr[(k - 256) * 256 + n];
  (which ? Wt2 : Wt1)[j] = (__bf16)v;
}

// x-half gather: xbase points at (row stride ROWB) destination of the x slot
__global__ void gather_x_kernel(const float* __restrict__ emb, const int* __restrict__ x_idx,
                                char* __restrict__ xbase, int N) {
  int wave = threadIdx.x >> 6, lane = threadIdx.x & 63;
  int i = blockIdx.x * 4 + wave;
  if (i >= N) return;
  int s = x_idx[i];
  float4 v = *(const float4*)(emb + (size_t)s * 256 + lane * 4);
  bf16x4 o = { (__bf16)v.x, (__bf16)v.y, (__bf16)v.z, (__bf16)v.w };
  *(bf16x4*)(xbase + (size_t)i * ROWB + lane * 8) = o;
}

// ---- mean aggregation -----------------------------------------------------
// Wave per node; 2x32-lane halves read DIFFERENT src rows at 16B/lane
// (dwordx4). Pair-unrolled: 4 rows (2KB) in flight. shfl_down(32) combine.

__global__ void sage_agg(const char* __restrict__ srcbase,  // row r: srcbase + r*ROWB, 256 bf16
                         char* __restrict__ dstbase,        // node i: dstbase + i*ROWB, 256 bf16
                         const int* __restrict__ csr, const int* __restrict__ cnt,
                         const int* __restrict__ offs, int N) {
  int wave = threadIdx.x >> 6, lane = threadIdx.x & 63;
  int i = blockIdx.x * 4 + wave;
  if (i >= N) return;
  int deg = cnt[i];
  const int* lp = csr + offs[i];
  int half = lane >> 5, l5 = lane & 31;

  f32x8 acc = (f32x8)0.f;
  int pairs = deg >> 1;
  int t = 0;
  for (; t + 2 <= pairs; t += 2) {  // 4 edges per iteration (2 per half)
    int s0 = lp[2 * t + half];
    int s1 = lp[2 * t + 2 + half];
    bf16x8 v0 = *(const bf16x8*)(srcbase + (size_t)s0 * ROWB + l5 * 16);
    bf16x8 v1 = *(const bf16x8*)(srcbase + (size_t)s1 * ROWB + l5 * 16);
#pragma unroll
    for (int k = 0; k < 8; ++k) acc[k] += (float)v0[k] + (float)v1[k];
  }
  if (t < pairs) {
    int s0 = lp[2 * t + half];
    bf16x8 v0 = *(const bf16x8*)(srcbase + (size_t)s0 * ROWB + l5 * 16);
#pragma unroll
    for (int k = 0; k < 8; ++k) acc[k] += (float)v0[k];
  }
  if ((deg & 1) && half == 0) {
    int s0 = lp[deg - 1];
    bf16x8 v0 = *(const bf16x8*)(srcbase + (size_t)s0 * ROWB + l5 * 16);
#pragma unroll
    for (int k = 0; k < 8; ++k) acc[k] += (float)v0[k];
  }

  float inv = 1.0f / (float)(deg > 0 ? deg : 1);
  bf16x8 o;
#pragma unroll
  for (int k = 0; k < 8; ++k) {
    float s = acc[k] + __shfl_down(acc[k], 32);
    o[k] = (__bf16)(s * inv);
  }
  if (half == 0)
    *(bf16x8*)(dstbase + (size_t)i * ROWB + l5 * 16) = o;
}

// ---- fused GEMM: out[M,256] = A[M,512] @ Wcat[512,256] + bias -------------
// BM=64, BN=256 (full), BK=32, 256 threads = 4 waves, wave tile 32x128.

template <int OUT_F32>
__global__ __launch_bounds__(256) void gemm_sage(const char* __restrict__ Abase,
                                                 const __bf16* __restrict__ Wt,
                                                 const float* __restrict__ bias,
                                                 char* __restrict__ outbase, int M) {
  __shared__ __align__(16) char lds[40960];  // 2 bufs x (A 4KB + B 16KB)
  const int tid = threadIdx.x;
  const int wave = tid >> 6, lane = tid & 63;
  const int r = lane & 15, q = lane >> 4;
  const int wm = wave >> 1, wn = wave & 1;
  const int row0 = blockIdx.x * 64;

  f32x4 acc[2][8];
#pragma unroll
  for (int t = 0; t < 2; ++t)
#pragma unroll
    for (int u = 0; u < 8; ++u) acc[t][u] = (f32x4)0.f;

  auto stage = [&](int kk, int buf) {
    char* lbase = lds + buf * 20480;
    int rowA = row0 + wave * 16 + r;
    rowA = rowA < M ? rowA : M - 1;  // clamp: garbage rows masked at store
    async_copy16(lbase + wave * 1024 + lane * 16,
                 Abase + (size_t)rowA * ROWB + (size_t)(kk * 32 + q * 8) * 2);
#pragma unroll
    for (int i = 0; i < 4; ++i) {
      int h = wave * 4 + i;
      async_copy16(lbase + 4096 + h * 1024 + lane * 16,
                   (const char*)Wt + ((size_t)(h * 16 + r) * 512 + kk * 32 + q * 8) * 2);
    }
  };

  stage(0, 0);
  for (int kk = 0; kk < 16; ++kk) {
    __syncthreads();  // compiler drains vmcnt before s_barrier -> staging done
    if (kk < 15) stage(kk + 1, (kk + 1) & 1);
    const char* lbase = lds + (kk & 1) * 20480;
    bf16x8 a0 = *(const bf16x8*)(lbase + (wm * 2 + 0) * 1024 + lane * 16);
    bf16x8 a1 = *(const bf16x8*)(lbase + (wm * 2 + 1) * 1024 + lane * 16);
#pragma unroll
    for (int u = 0; u < 8; ++u) {
      bf16x8 b = *(const bf16x8*)(lbase + 4096 + (wn * 8 + u) * 1024 + lane * 16);
      acc[0][u] = __builtin_amdgcn_mfma_f32_16x16x32_bf16(a0, b, acc[0][u], 0, 0, 0);
      acc[1][u] = __builtin_amdgcn_mfma_f32_16x16x32_bf16(a1, b, acc[1][u], 0, 0, 0);
    }
  }

  // epilogue. All global A reads drained at the kk=15 barrier, so in-place
  // fp32 overwrite of this block's own rows (sole owner, BN=256) is safe.
#pragma unroll
  for (int t = 0; t < 2; ++t) {
    int rbase = row0 + wm * 32 + t * 16 + q * 4;
#pragma unroll
    for (int u = 0; u < 8; ++u) {
      int col = wn * 128 + u * 16 + r;
      float bv = bias[col];
#pragma unroll
      for (int j = 0; j < 4; ++j) {
        int row = rbase + j;
        if (row < M) {
          float v = acc[t][u][j] + bv;
          if (OUT_F32)
            *(float*)(outbase + (size_t)row * ROWB + col * 4) = v;
          else
            *(__bf16*)(outbase + (size_t)row * ROWB + 512 + col * 2) = (__bf16)v;
        }
      }
    }
  }
}

// ---- final index gathers --------------------------------------------------

__global__ void gather_out_kernel(const float* __restrict__ x2, const int* __restrict__ drug,
                                  const int* __restrict__ se, float* __restrict__ out,
                                  int nd, int ns) {
  int wave = threadIdx.x >> 6, lane = threadIdx.x & 63;
  int ro = blockIdx.x * 4 + wave;
  if (ro >= nd + ns) return;
  int node = (ro < nd) ? drug[ro] : se[ro - nd];
  float4 v = *(const float4*)(x2 + (size_t)node * 256 + lane * 4);
  *(float4*)(out + (size_t)ro * 256 + lane * 4) = v;
}

// ---------------------------------------------------------------------------

extern "C" void kernel_launch(void* const* d_in, const int* in_sizes, int n_in,
                              void* d_out, int out_size, void* d_ws, size_t ws_size,
                              hipStream_t stream) {
  const float* emb  = (const float*)d_in[0];
  const float* W1l  = (const float*)d_in[1];
  const float* b1l  = (const float*)d_in[2];
  const float* W1r  = (const float*)d_in[3];
  const float* W2l  = (const float*)d_in[4];
  const float* b2l  = (const float*)d_in[5];
  const float* W2r  = (const float*)d_in[6];
  const int* x_idx  = (const int*)d_in[7];
  const int* edge   = (const int*)d_in[8];
  const int* drug   = (const int*)d_in[9];
  const int* se     = (const int*)d_in[10];

  const int N = in_sizes[7];       // 100000
  const int E = in_sizes[8] / 2;   // 1600000
  const int nd = in_sizes[9], ns = in_sizes[10];
  const int* esrc = edge;
  const int* edst = edge + E;
  const int NBUK = (N + 63) >> 6;  // 1563 (<= MAXBUK)
  const int chunk = (E + NPART - 1) / NPART;

  // persistent workspace carve (~110 MB)
  char* ws = (char*)d_ws;
  size_t off = 0;
  char* xA1 = ws;                       off += (size_t)((N + 127) & ~127) * ROWB;
  __bf16* Wt1 = (__bf16*)(ws + off);    off += 512 * 256 * 2;
  __bf16* Wt2 = (__bf16*)(ws + off);    off += 512 * 256 * 2;
  int* cnt  = (int*)(ws + off);         off += ((size_t)N * 4 + 255) & ~(size_t)255;
  int* offs = (int*)(ws + off);         off += ((size_t)N * 4 + 255) & ~(size_t)255;
  int* csr  = (int*)(ws + off);         off += ((size_t)E * 4 + 255) & ~(size_t)255;
  int* bsum = (int*)(ws + off);         off += 4096;
  int* bbase = (int*)(ws + off);        off += 4096;
  // transient arrays overlay xA1 (all dead before gather_x writes xA1):
  int* ebuf = (int*)xA1;                         // E ints (6.4 MB)
  int* hmat = (int*)(xA1 + (8u << 20));          // NPART*NBUK ints (~1.6 MB)
  int* btot = (int*)(xA1 + (16u << 20));         // NBUK ints
  int* boff = (int*)(xA1 + (16u << 20) + 16384); // NBUK ints

  // d_out carve: [drug nd*256 | se ns*256 | x2 N*256] fp32
  float* outp = (float*)d_out;
  float* x2 = outp + (size_t)(nd + ns) * 256;
  char* scratch2 = (char*)x2;  // rows of 1KB: [mean2 bf16 | x1 bf16] -> x2 fp32

  const int NB = (N + 255) / 256;        // 391 (<=512 required by scan_tops)
  const int QB = (N + 3) / 4;
  const int GB = (N + 63) / 64;

  prep_w_kernel<<<(2 * 131072) / 256, 256, 0, stream>>>(W1l, W1r, W2l, W2r, Wt1, Wt2);

  // CSR build, deterministic (no global atomics)
  bin_count<<<NPART, 256, 0, stream>>>(edst, hmat, E, chunk, NBUK);
  col_scan<<<NBUK, NPART, 0, stream>>>(hmat, btot, NBUK);
  bucket_scan<<<1, 1024, 0, stream>>>(btot, boff, NBUK);
  part_write<<<NPART, 256, 0, stream>>>(esrc, edst, hmat, boff, ebuf, E, chunk, NBUK);
  node_hist<<<NBUK, 256, 0, stream>>>(ebuf, boff, btot, cnt, N);
  scan_block_sums<<<NB, 256, 0, stream>>>(cnt, bsum, N);
  scan_tops<<<1, 512, 0, stream>>>(bsum, bbase, NB);
  scan_final<<<NB, 256, 0, stream>>>(cnt, bbase, offs, N);
  csr_write<<<NBUK, 256, 0, stream>>>(ebuf, boff, btot, offs, csr, N);

  gather_x_kernel<<<QB, 256, 0, stream>>>(emb, x_idx, xA1 + 512, N);
  // layer 1
  sage_agg<<<QB, 256, 0, stream>>>(xA1 + 512, xA1, csr, cnt, offs, N);
  gemm_sage<0><<<GB, 256, 0, stream>>>(xA1, Wt1, b1l, scratch2, N);
  // layer 2
  sage_agg<<<QB, 256, 0, stream>>>(scratch2 + 512, scratch2, csr, cnt, offs, N);
  gemm_sage<1><<<GB, 256, 0, stream>>>(scratch2, Wt2, b2l, scratch2, N);

  gather_out_kernel<<<(nd + ns + 3) / 4, 256, 0, stream>>>(x2, drug, se, outp, nd, ns);
}